// Round 2
// baseline (650.273 us; speedup 1.0000x reference)
//
#include <hip/hip_runtime.h>

// CrossAttUnit: per-segment cross-attention, SPLIT into two latency-friendly kernels.
//   prep_kq: k,q -> transposed split-bf16 planes (128 KB, L2-resident)
//   proj:    yk = Y @ k ; yq = Yhat @ q for ALL tokens (barrier-free streaming GEMM),
//            output = per-segment split-bf16 hi/lo planes, pre-swizzled for LDS (128 MB ws)
//   mix:     per segment: stage 32 KB planes -> LDS, M = (1/8) yk @ yq^T (split-bf16 MFMA),
//            softmax rows + column-normalize fully in-register, write W.
// Numerics bit-identical to the fused V2 kernel (same rounding chain / product set / order).
// Fallback: if ws_size can't hold the 128 MB intermediate, run the fused V2 kernel.

#define H  256
#define D  64
#define L  64

typedef __attribute__((ext_vector_type(8))) short frag_b;   // 8 x bf16 (4 VGPR)
typedef __attribute__((ext_vector_type(4))) float frag_acc; // 4 x fp32

__device__ inline unsigned short f32_bf16_rne(float f) {
    unsigned u = __float_as_uint(f);
    u += 0x7FFFu + ((u >> 16) & 1u);   // round-to-nearest-even on sign-magnitude bits
    return (unsigned short)(u >> 16);
}
__device__ inline float bf16_f32(unsigned short h) {
    return __uint_as_float(((unsigned)h) << 16);
}

// Offset (in shorts) of element (row,col) in a 64x64 bf16 plane.
// Row = 128 B = 8 chunks of 16 B; chunk index XORed with row&7 so a
// 16-row column-strided ds_read_b128 lands on 8 distinct chunk positions
// (2-way bank aliasing = free). Same function on write and read sides.
__device__ inline int pswz(int row, int col) {
    return (row << 6) + ((((col >> 3) ^ row) & 7) << 3) + (col & 7);
}

// Transpose + hi/lo split k,q into ws:
//  planes[0]      = kT_hi[64][256], planes[16384]  = kT_lo
//  planes[32768]  = qT_hi,          planes[49152]  = qT_lo
__global__ void prep_kq(const float* __restrict__ k, const float* __restrict__ q,
                        unsigned short* __restrict__ planes) {
    int tid = blockIdx.x * 256 + threadIdx.x;            // 0..32767
    const float* src = (tid < H * D) ? k : q;
    int base = (tid < H * D) ? 0 : 2 * H * D;
    int e = tid & (H * D - 1);
    int h = e >> 6, d = e & 63;                          // k[h][d]
    float x = src[e];
    unsigned short hi = f32_bf16_rne(x);
    float rem = x - bf16_f32(hi);
    unsigned short lo = f32_bf16_rne(rem);
    int o = d * H + h;                                   // transposed [d][h]
    planes[base + o] = hi;
    planes[base + H * D + o] = lo;
}

// ================= proj: streaming projection GEMM =================
// grid (N/128, 2); blockIdx.y: 0 -> yk from Y, 1 -> yq from Yhat.
// Each wave computes a 32-row x 64-col tile (split-bf16, 3 products) and writes
// hi/lo planes to pl2 at [seg][mat][hi|lo][pswz(row,col)] (= mix's exact LDS image).
__global__ __launch_bounds__(256, 4) void proj(
        const float* __restrict__ y, const float* __restrict__ yhat,
        const unsigned short* __restrict__ kq, unsigned short* __restrict__ pl2) {
    const int mat  = blockIdx.y;
    const float* src = mat ? yhat : y;
    const frag_b* bph = (const frag_b*)(kq + mat * 2 * H * D); // hi plane, short8 units
    const frag_b* bpl = bph + (H * D) / 8;                     // lo plane
    const int tid  = threadIdx.x;
    const int wave = tid >> 6;
    const int lane = tid & 63;
    const int ln   = lane & 15;
    const int kg   = lane >> 4;
    const int row0 = blockIdx.x * 128 + wave * 32;

    const frag_acc zf = {0.f, 0.f, 0.f, 0.f};
    frag_acc acc[2][4];
    #pragma unroll
    for (int rt = 0; rt < 2; rt++)
        #pragma unroll
        for (int t = 0; t < 4; t++) acc[rt][t] = zf;

    const float* abase = src + ((size_t)(row0 + ln)) * H + kg * 8;

    #pragma unroll 2
    for (int ks = 0; ks < 8; ks++) {
        const int kb = ks * 32;
        // issue all global loads for this k-slice up front (4 A + 8 B frags)
        float4 v[2][2];
        #pragma unroll
        for (int rt = 0; rt < 2; rt++) {
            const float4* ap = (const float4*)(abase + (size_t)rt * 16 * H + kb);
            v[rt][0] = ap[0];
            v[rt][1] = ap[1];
        }
        frag_b bh[4], bl[4];
        #pragma unroll
        for (int t = 0; t < 4; t++) {
            int n = t * 16 + ln;
            bh[t] = bph[n * (H / 8) + ks * 4 + kg];
            bl[t] = bpl[n * (H / 8) + ks * 4 + kg];
        }
        frag_b ah[2], al[2];
        #pragma unroll
        for (int rt = 0; rt < 2; rt++) {
            float xs[8] = {v[rt][0].x, v[rt][0].y, v[rt][0].z, v[rt][0].w,
                           v[rt][1].x, v[rt][1].y, v[rt][1].z, v[rt][1].w};
            #pragma unroll
            for (int j = 0; j < 8; j++) {
                unsigned short hb = f32_bf16_rne(xs[j]);
                ah[rt][j] = (short)hb;
                al[rt][j] = (short)f32_bf16_rne(xs[j] - bf16_f32(hb));
            }
        }
        #pragma unroll
        for (int t = 0; t < 4; t++)
            #pragma unroll
            for (int rt = 0; rt < 2; rt++) {
                acc[rt][t] = __builtin_amdgcn_mfma_f32_16x16x32_bf16(ah[rt], bh[t], acc[rt][t], 0, 0, 0);
                acc[rt][t] = __builtin_amdgcn_mfma_f32_16x16x32_bf16(ah[rt], bl[t], acc[rt][t], 0, 0, 0);
                acc[rt][t] = __builtin_amdgcn_mfma_f32_16x16x32_bf16(al[rt], bh[t], acc[rt][t], 0, 0, 0);
            }
    }

    // Epilogue: split once into (hi,lo) bf16, store to swizzled per-segment planes.
    // C/D layout: col = lane&15, row = (lane>>4)*4 + i (m89/m91).
    #pragma unroll
    for (int rt = 0; rt < 2; rt++)
        #pragma unroll
        for (int t = 0; t < 4; t++)
            #pragma unroll
            for (int i = 0; i < 4; i++) {
                int rg  = row0 + rt * 16 + kg * 4 + i;
                int seg = rg >> 6, r = rg & 63;
                int col = t * 16 + ln;
                int o   = pswz(r, col);
                unsigned short* mb = pl2 + (size_t)seg * 16384 + mat * 8192;
                float x = acc[rt][t][i];
                unsigned short hb = f32_bf16_rne(x);
                mb[o]        = hb;
                mb[4096 + o] = f32_bf16_rne(x - bf16_f32(hb));
            }
}

// ================= mix: per-segment attention =================
__global__ __launch_bounds__(256, 5) void mix(
        const unsigned short* __restrict__ pl2, float* __restrict__ out) {
    // LDS = exact image of the segment's 32 KB plane block:
    // [ykH 4096][ykL 4096][yqH 4096][yqL 4096] shorts, pre-swizzled by proj.
    __shared__ __align__(16) unsigned short s_pl[4 * L * D];

    const int b    = blockIdx.x;
    const int tid  = threadIdx.x;
    const int wave = tid >> 6;
    const int lane = tid & 63;
    const int ln   = lane & 15;
    const int kg   = lane >> 4;

    // -------- stage 32 KB, coalesced float4 --------
    {
        const float4* g4 = (const float4*)(pl2 + (size_t)b * 16384);
        float4* s4 = (float4*)s_pl;
        #pragma unroll
        for (int i = 0; i < 8; i++) s4[i * 256 + tid] = g4[i * 256 + tid];
    }
    __syncthreads();

    // -------- Phase 2: M = (1/8) * yk @ yq^T --------
    const unsigned short* ykH = s_pl;
    const unsigned short* ykL = s_pl + L * D;
    const unsigned short* yqH = s_pl + 2 * L * D;
    const unsigned short* yqL = s_pl + 3 * L * D;

    const frag_acc zf = {0.f, 0.f, 0.f, 0.f};
    frag_acc mac[4];
    #pragma unroll
    for (int t = 0; t < 4; t++) mac[t] = zf;

    #pragma unroll
    for (int dk = 0; dk < 2; dk++) {
        const int colb = dk * 32 + kg * 8;
        frag_b ah = *(const frag_b*)(ykH + pswz(wave * 16 + ln, colb));
        frag_b al = *(const frag_b*)(ykL + pswz(wave * 16 + ln, colb));
        #pragma unroll
        for (int t = 0; t < 4; t++) {
            frag_b bh = *(const frag_b*)(yqH + pswz(t * 16 + ln, colb));
            frag_b bl = *(const frag_b*)(yqL + pswz(t * 16 + ln, colb));
            mac[t] = __builtin_amdgcn_mfma_f32_16x16x32_bf16(ah, bh, mac[t], 0, 0, 0);
            mac[t] = __builtin_amdgcn_mfma_f32_16x16x32_bf16(ah, bl, mac[t], 0, 0, 0);
            mac[t] = __builtin_amdgcn_mfma_f32_16x16x32_bf16(al, bh, mac[t], 0, 0, 0);
        }
    }
    __syncthreads();   // all plane reads drained -> safe to alias s_cs onto s_pl

    // -------- Phase 3: softmax rows + column-normalize, in-register --------
    // Lane holds M[row = wave*16 + kg*4 + i][col = t*16 + ln] in mac[t][i].
    float* s_cs = (float*)s_pl;   // 4 waves * 64 cols, aliases dead planes

    float a[4][4];
    float colpart[4] = {0.f, 0.f, 0.f, 0.f};
    #pragma unroll
    for (int i = 0; i < 4; i++) {
        float v0 = 0.125f * mac[0][i], v1 = 0.125f * mac[1][i];
        float v2 = 0.125f * mac[2][i], v3 = 0.125f * mac[3][i];
        float mx = fmaxf(fmaxf(v0, v1), fmaxf(v2, v3));
        #pragma unroll
        for (int off = 8; off >= 1; off >>= 1) mx = fmaxf(mx, __shfl_xor(mx, off, 64));
        float e0 = __expf(v0 - mx), e1 = __expf(v1 - mx);
        float e2 = __expf(v2 - mx), e3 = __expf(v3 - mx);
        float s = (e0 + e1) + (e2 + e3);
        #pragma unroll
        for (int off = 8; off >= 1; off >>= 1) s += __shfl_xor(s, off, 64);
        float rs = 1.f / s;
        a[0][i] = e0 * rs + 1e-6f; a[1][i] = e1 * rs + 1e-6f;
        a[2][i] = e2 * rs + 1e-6f; a[3][i] = e3 * rs + 1e-6f;
        colpart[0] += a[0][i]; colpart[1] += a[1][i];
        colpart[2] += a[2][i]; colpart[3] += a[3][i];
    }
    #pragma unroll
    for (int t = 0; t < 4; t++) {
        colpart[t] += __shfl_xor(colpart[t], 16, 64);
        colpart[t] += __shfl_xor(colpart[t], 32, 64);
    }
    s_cs[wave * 64 + kg * 16 + ln] = colpart[kg];
    __syncthreads();

    float* ob = out + (size_t)b * (L * L);
    #pragma unroll
    for (int t = 0; t < 4; t++) {
        int c = t * 16 + ln;
        float inv = 1.f / (s_cs[c] + s_cs[64 + c] + s_cs[128 + c] + s_cs[192 + c]);
        #pragma unroll
        for (int i = 0; i < 4; i++)
            ob[(wave * 16 + kg * 4 + i) * 64 + c] = a[t][i] * inv;
    }
}

// ================= fallback: fused V2 kernel (used only if ws too small) ========
__global__ __launch_bounds__(256, 5) void cross_attn_fused(
        const float* __restrict__ yhat, const float* __restrict__ y,
        const unsigned short* __restrict__ planes, float* __restrict__ out) {
    __shared__ __align__(16) unsigned short s_pl[4 * L * D];

    const int b    = blockIdx.x;
    const int tid  = threadIdx.x;
    const int wave = tid >> 6;
    const int lane = tid & 63;
    const int ln   = lane & 15;
    const int kg   = lane >> 4;

    const bool isQ = (wave >= 2);
    const float* src = isQ ? yhat : y;
    const frag_b* bph = (const frag_b*)(planes + (isQ ? 2 * H * D : 0));
    const frag_b* bpl = bph + (H * D) / 8;
    const int rowbase = (wave & 1) * 32;

    const frag_acc zf = {0.f, 0.f, 0.f, 0.f};
    frag_acc acc[2][4];
    #pragma unroll
    for (int rt = 0; rt < 2; rt++)
        #pragma unroll
        for (int t = 0; t < 4; t++) acc[rt][t] = zf;

    const float* abase = src + ((size_t)b * L + rowbase + ln) * H + kg * 8;

    #pragma unroll 2
    for (int ks = 0; ks < 8; ks++) {
        const int kb = ks * 32;
        float4 v[2][2];
        #pragma unroll
        for (int rt = 0; rt < 2; rt++) {
            const float4* ap = (const float4*)(abase + (size_t)rt * 16 * H + kb);
            v[rt][0] = ap[0];
            v[rt][1] = ap[1];
        }
        frag_b ah[2], al[2];
        #pragma unroll
        for (int rt = 0; rt < 2; rt++) {
            float xs[8] = {v[rt][0].x, v[rt][0].y, v[rt][0].z, v[rt][0].w,
                           v[rt][1].x, v[rt][1].y, v[rt][1].z, v[rt][1].w};
            #pragma unroll
            for (int j = 0; j < 8; j++) {
                unsigned short hb = f32_bf16_rne(xs[j]);
                ah[rt][j] = (short)hb;
                al[rt][j] = (short)f32_bf16_rne(xs[j] - bf16_f32(hb));
            }
        }
        #pragma unroll
        for (int t = 0; t < 4; t++) {
            int n = t * 16 + ln;
            frag_b bh = bph[n * (H / 8) + ks * 4 + kg];
            frag_b bl = bpl[n * (H / 8) + ks * 4 + kg];
            #pragma unroll
            for (int rt = 0; rt < 2; rt++) {
                acc[rt][t] = __builtin_amdgcn_mfma_f32_16x16x32_bf16(ah[rt], bh, acc[rt][t], 0, 0, 0);
                acc[rt][t] = __builtin_amdgcn_mfma_f32_16x16x32_bf16(ah[rt], bl, acc[rt][t], 0, 0, 0);
                acc[rt][t] = __builtin_amdgcn_mfma_f32_16x16x32_bf16(al[rt], bh, acc[rt][t], 0, 0, 0);
            }
        }
    }
    {
        unsigned short* dstH = s_pl + (isQ ? 2 * L * D : 0);
        unsigned short* dstL = dstH + L * D;
        #pragma unroll
        for (int rt = 0; rt < 2; rt++)
            #pragma unroll
            for (int t = 0; t < 4; t++)
                #pragma unroll
                for (int i = 0; i < 4; i++) {
                    int row = rowbase + rt * 16 + kg * 4 + i;
                    int col = t * 16 + ln;
                    float x = acc[rt][t][i];
                    unsigned short hb = f32_bf16_rne(x);
                    int o = pswz(row, col);
                    dstH[o] = hb;
                    dstL[o] = f32_bf16_rne(x - bf16_f32(hb));
                }
    }
    __syncthreads();

    const unsigned short* ykH = s_pl;
    const unsigned short* ykL = s_pl + L * D;
    const unsigned short* yqH = s_pl + 2 * L * D;
    const unsigned short* yqL = s_pl + 3 * L * D;

    frag_acc mac[4];
    #pragma unroll
    for (int t = 0; t < 4; t++) mac[t] = zf;

    #pragma unroll
    for (int dk = 0; dk < 2; dk++) {
        const int colb = dk * 32 + kg * 8;
        frag_b ah = *(const frag_b*)(ykH + pswz(wave * 16 + ln, colb));
        frag_b al = *(const frag_b*)(ykL + pswz(wave * 16 + ln, colb));
        #pragma unroll
        for (int t = 0; t < 4; t++) {
            frag_b bh = *(const frag_b*)(yqH + pswz(t * 16 + ln, colb));
            frag_b bl = *(const frag_b*)(yqL + pswz(t * 16 + ln, colb));
            mac[t] = __builtin_amdgcn_mfma_f32_16x16x32_bf16(ah, bh, mac[t], 0, 0, 0);
            mac[t] = __builtin_amdgcn_mfma_f32_16x16x32_bf16(ah, bl, mac[t], 0, 0, 0);
            mac[t] = __builtin_amdgcn_mfma_f32_16x16x32_bf16(al, bh, mac[t], 0, 0, 0);
        }
    }
    __syncthreads();

    float* s_cs = (float*)s_pl;
    float a[4][4];
    float colpart[4] = {0.f, 0.f, 0.f, 0.f};
    #pragma unroll
    for (int i = 0; i < 4; i++) {
        float v0 = 0.125f * mac[0][i], v1 = 0.125f * mac[1][i];
        float v2 = 0.125f * mac[2][i], v3 = 0.125f * mac[3][i];
        float mx = fmaxf(fmaxf(v0, v1), fmaxf(v2, v3));
        #pragma unroll
        for (int off = 8; off >= 1; off >>= 1) mx = fmaxf(mx, __shfl_xor(mx, off, 64));
        float e0 = __expf(v0 - mx), e1 = __expf(v1 - mx);
        float e2 = __expf(v2 - mx), e3 = __expf(v3 - mx);
        float s = (e0 + e1) + (e2 + e3);
        #pragma unroll
        for (int off = 8; off >= 1; off >>= 1) s += __shfl_xor(s, off, 64);
        float rs = 1.f / s;
        a[0][i] = e0 * rs + 1e-6f; a[1][i] = e1 * rs + 1e-6f;
        a[2][i] = e2 * rs + 1e-6f; a[3][i] = e3 * rs + 1e-6f;
        colpart[0] += a[0][i]; colpart[1] += a[1][i];
        colpart[2] += a[2][i]; colpart[3] += a[3][i];
    }
    #pragma unroll
    for (int t = 0; t < 4; t++) {
        colpart[t] += __shfl_xor(colpart[t], 16, 64);
        colpart[t] += __shfl_xor(colpart[t], 32, 64);
    }
    s_cs[wave * 64 + kg * 16 + ln] = colpart[kg];
    __syncthreads();

    float* ob = out + (size_t)b * (L * L);
    #pragma unroll
    for (int t = 0; t < 4; t++) {
        int c = t * 16 + ln;
        float inv = 1.f / (s_cs[c] + s_cs[64 + c] + s_cs[128 + c] + s_cs[192 + c]);
        #pragma unroll
        for (int i = 0; i < 4; i++)
            ob[(wave * 16 + kg * 4 + i) * 64 + c] = a[t][i] * inv;
    }
}

extern "C" void kernel_launch(void* const* d_in, const int* in_sizes, int n_in,
                              void* d_out, int out_size, void* d_ws, size_t ws_size,
                              hipStream_t stream) {
    const float* yhat = (const float*)d_in[0];
    const float* y    = (const float*)d_in[1];
    const float* k    = (const float*)d_in[2];
    const float* q    = (const float*)d_in[3];
    float* outp = (float*)d_out;
    unsigned short* planes = (unsigned short*)d_ws;   // 128 KB k/q planes

    const int N = in_sizes[0] / H;    // 262144
    const int B = N / L;              // 4096

    prep_kq<<<(2 * H * D) / 256, 256, 0, stream>>>(k, q, planes);

    // per-token intermediate: 64 d * 2 planes * 2 mats * 2 B = 512 B
    const size_t need = 128 * 1024 + (size_t)N * 512;
    if (ws_size >= need) {
        unsigned short* pl2 = (unsigned short*)((char*)d_ws + 128 * 1024);
        proj<<<dim3(N / 128, 2), 256, 0, stream>>>(y, yhat, planes, pl2);
        mix<<<B, 256, 0, stream>>>(pl2, outp);
    } else {
        cross_attn_fused<<<B, 256, 0, stream>>>(yhat, y, planes, outp);
    }
}